// Round 1
// baseline (261.301 us; speedup 1.0000x reference)
//
#include <hip/hip_runtime.h>
#include <stdint.h>
#include <stddef.h>

#define AS1 __attribute__((address_space(1)))
#define AS3 __attribute__((address_space(3)))

typedef short bf16x8 __attribute__((ext_vector_type(8)));
typedef float f32x4 __attribute__((ext_vector_type(4)));
typedef unsigned short u16x8 __attribute__((ext_vector_type(8)));

static constexpr int N = 4096;
static constexpr int K = 2048;
static constexpr int BM = 128;
static constexpr int BK = 64;
static constexpr int TILES = N / BM;        // 32
static constexpr int NBLK = TILES * TILES;  // 1024 tiles per pair

// round-to-nearest-even f32 -> bf16 (inputs are finite normals; no NaN path)
__device__ __forceinline__ unsigned short f2bf(float f) {
  union { float f; uint32_t u; } v; v.f = f;
  return (unsigned short)((v.u + 0x7FFFu + ((v.u >> 16) & 1u)) >> 16);
}

// Per-row: x2[row] = sum_k X[row][k]^2 (f64 accumulate, f32 store — storage
// error cancels exactly in the 1/1/-2 combination). Optionally writes bf16 copy.
__global__ __launch_bounds__(256) void prep_kernel(
    const float* __restrict__ X, const float* __restrict__ Y,
    float* __restrict__ x2, float* __restrict__ y2,
    unsigned short* __restrict__ Xb, unsigned short* __restrict__ Yb, int wb) {
  const int row = blockIdx.x;
  const float* src = blockIdx.y ? Y : X;
  float* nrm = blockIdx.y ? y2 : x2;
  unsigned short* dst = blockIdx.y ? Yb : Xb;
  const size_t base = (size_t)row * K + threadIdx.x * 8;
  const float4 a = *(const float4*)(src + base);
  const float4 b = *(const float4*)(src + base + 4);
  double s = (double)a.x * a.x + (double)a.y * a.y + (double)a.z * a.z +
             (double)a.w * a.w + (double)b.x * b.x + (double)b.y * b.y +
             (double)b.z * b.z + (double)b.w * b.w;
  if (wb) {
    u16x8 o;
    o[0] = f2bf(a.x); o[1] = f2bf(a.y); o[2] = f2bf(a.z); o[3] = f2bf(a.w);
    o[4] = f2bf(b.x); o[5] = f2bf(b.y); o[6] = f2bf(b.z); o[7] = f2bf(b.w);
    *(u16x8*)(dst + base) = o;
  }
#pragma unroll
  for (int off = 32; off; off >>= 1) s += __shfl_down(s, off);
  __shared__ double red[4];
  if ((threadIdx.x & 63) == 0) red[threadIdx.x >> 6] = s;
  __syncthreads();
  if (threadIdx.x == 0) nrm[row] = (float)(red[0] + red[1] + red[2] + red[3]);
}

// Fused bf16 GEMM (C = A * B^T over rows) + expm1 epilogue + block reduction.
// MODE 0: A/B are pre-converted bf16, staged via global_load_lds (16B) with
//         pre-swizzled global source (rule #21) + XOR-swizzled ds_read (T2).
// MODE 1: A/B are f32; reg-stage + convert + swizzled ds_write (ws fallback).
template <int MODE>
__global__ __launch_bounds__(256) void mmd_gemm(
    const void* __restrict__ Xp, const void* __restrict__ Yp,
    const float* __restrict__ x2, const float* __restrict__ y2,
    double* __restrict__ partials) {
  const int p = blockIdx.y;                      // 0: XX, 1: YY, 2: XY
  const void* Ap = (p == 1) ? Yp : Xp;
  const void* Bp = (p == 0) ? Xp : Yp;
  const float* rn = (p == 1) ? y2 : x2;
  const float* cn = (p == 0) ? x2 : y2;
  const double wgt = (p == 2) ? -2.0 : 1.0;

  const int bx = blockIdx.x;
  const int i0 = (bx & (TILES - 1)) * BM;
  const int j0 = (bx / TILES) * BM;

  __shared__ __align__(16) unsigned short As[BM * BK];
  __shared__ __align__(16) unsigned short Bs[BM * BK];

  const int tid = threadIdx.x;
  const int w = tid >> 6, l = tid & 63;
  const int m_base = (w >> 1) * 64, n_base = (w & 1) * 64;

  f32x4 acc[4][4] = {};

  for (int k0 = 0; k0 < K; k0 += BK) {
    if constexpr (MODE == 0) {
      const unsigned short* A = (const unsigned short*)Ap;
      const unsigned short* B = (const unsigned short*)Bp;
#pragma unroll
      for (int u = 0; u < 4; ++u) {
        const int seg = w * 4 + u;          // 16 segments x 64 chunks of 16B
        const int f = seg * 64 + l;         // chunk index in tile
        const int row = f >> 3;             // tile row (0..127)
        const int scol = ((f & 7) ^ (row & 7)) * 8;  // inverse-swizzled source col
        __builtin_amdgcn_global_load_lds(
            (const AS1 unsigned int*)(A + (size_t)(i0 + row) * K + k0 + scol),
            (AS3 unsigned int*)(As + seg * 512), 16, 0, 0);
        __builtin_amdgcn_global_load_lds(
            (const AS1 unsigned int*)(B + (size_t)(j0 + row) * K + k0 + scol),
            (AS3 unsigned int*)(Bs + seg * 512), 16, 0, 0);
      }
    } else {
      const float* A = (const float*)Ap;
      const float* B = (const float*)Bp;
#pragma unroll
      for (int u = 0; u < 4; ++u) {
        const int f = u * 256 + tid;
        const int row = f >> 3;
        const int cir = f & 7;
        const int dstb = row * 128 + ((cir ^ (row & 7)) * 16);  // swizzled LDS byte
        {
          const float* g = A + (size_t)(i0 + row) * K + k0 + cir * 8;
          const float4 v0 = *(const float4*)g;
          const float4 v1 = *(const float4*)(g + 4);
          u16x8 o;
          o[0] = f2bf(v0.x); o[1] = f2bf(v0.y); o[2] = f2bf(v0.z); o[3] = f2bf(v0.w);
          o[4] = f2bf(v1.x); o[5] = f2bf(v1.y); o[6] = f2bf(v1.z); o[7] = f2bf(v1.w);
          *(u16x8*)((char*)As + dstb) = o;
        }
        {
          const float* g = B + (size_t)(j0 + row) * K + k0 + cir * 8;
          const float4 v0 = *(const float4*)g;
          const float4 v1 = *(const float4*)(g + 4);
          u16x8 o;
          o[0] = f2bf(v0.x); o[1] = f2bf(v0.y); o[2] = f2bf(v0.z); o[3] = f2bf(v0.w);
          o[4] = f2bf(v1.x); o[5] = f2bf(v1.y); o[6] = f2bf(v1.z); o[7] = f2bf(v1.w);
          *(u16x8*)((char*)Bs + dstb) = o;
        }
      }
    }
    __syncthreads();

#pragma unroll
    for (int kk = 0; kk < BK; kk += 32) {
      bf16x8 af[4], bfr[4];
      const int lr = l & 15;
      const int ch = (kk >> 3) + (l >> 4);  // 16B chunk within the 128B row
#pragma unroll
      for (int mi = 0; mi < 4; ++mi) {
        const int r = m_base + mi * 16 + lr;
        af[mi] = *(const bf16x8*)((const char*)As + r * 128 + ((ch ^ (r & 7)) * 16));
      }
#pragma unroll
      for (int ni = 0; ni < 4; ++ni) {
        const int r = n_base + ni * 16 + lr;
        bfr[ni] = *(const bf16x8*)((const char*)Bs + r * 128 + ((ch ^ (r & 7)) * 16));
      }
#pragma unroll
      for (int mi = 0; mi < 4; ++mi)
#pragma unroll
        for (int ni = 0; ni < 4; ++ni)
          acc[mi][ni] = __builtin_amdgcn_mfma_f32_16x16x32_bf16(
              af[mi], bfr[ni], acc[mi][ni], 0, 0, 0);
    }
    __syncthreads();
  }

  // Epilogue: v = expm1(-sqdist/D^2) via Taylor (|t| < 1.3e-3, trunc < 1e-13).
  // The "+1" of exp cancels analytically across the 1/1/-2 pair weights.
  const float ce = -1.0f / (2048.0f * 2048.0f);
  double s = 0.0;
  const int lr = l & 15, lq = l >> 4;
#pragma unroll
  for (int mi = 0; mi < 4; ++mi) {
#pragma unroll
    for (int r4 = 0; r4 < 4; ++r4) {
      const float rv = rn[i0 + m_base + mi * 16 + lq * 4 + r4];
#pragma unroll
      for (int ni = 0; ni < 4; ++ni) {
        const float cv = cn[j0 + n_base + ni * 16 + lr];
        const float t = ce * (rv + cv - 2.0f * acc[mi][ni][r4]);
        const float v =
            t * (1.0f + t * (0.5f + t * (0.16666667f + t * 0.041666668f)));
        s += (double)v;
      }
    }
  }
#pragma unroll
  for (int off = 32; off; off >>= 1) s += __shfl_down(s, off);
  __shared__ double red[4];
  if (l == 0) red[w] = s;
  __syncthreads();
  if (tid == 0) partials[p * NBLK + bx] = wgt * (red[0] + red[1] + red[2] + red[3]);
}

__global__ __launch_bounds__(256) void finalize_kernel(
    const double* __restrict__ partials, float* __restrict__ out) {
  double s = 0.0;
  for (int i = threadIdx.x; i < 3 * NBLK; i += 256) s += partials[i];
#pragma unroll
  for (int off = 32; off; off >>= 1) s += __shfl_down(s, off);
  __shared__ double red[4];
  if ((threadIdx.x & 63) == 0) red[threadIdx.x >> 6] = s;
  __syncthreads();
  if (threadIdx.x == 0)
    out[0] = (float)((red[0] + red[1] + red[2] + red[3]) *
                     (1.0 / ((double)N * (double)N)));
}

extern "C" void kernel_launch(void* const* d_in, const int* in_sizes, int n_in,
                              void* d_out, int out_size, void* d_ws,
                              size_t ws_size, hipStream_t stream) {
  const float* X = (const float*)d_in[0];
  const float* Y = (const float*)d_in[1];
  char* ws = (char*)d_ws;

  // ws layout: [0,24576) partials (3*1024 f64) | [24576,+16K) x2 | [40960,+16K) y2
  //            [65536, +16MB) Xb bf16 | [+16MB) Yb bf16
  double* partials = (double*)ws;
  float* x2 = (float*)(ws + 24576);
  float* y2 = (float*)(ws + 24576 + 16384);
  unsigned short* Xb = (unsigned short*)(ws + 65536);
  unsigned short* Yb = Xb + (size_t)N * K;
  const size_t need_fast = (size_t)65536 + (size_t)2 * N * K * 2;
  const bool fast = ws_size >= need_fast;

  prep_kernel<<<dim3(N, 2), 256, 0, stream>>>(X, Y, x2, y2, Xb, Yb, fast ? 1 : 0);
  if (fast)
    mmd_gemm<0><<<dim3(NBLK, 3), 256, 0, stream>>>(Xb, Yb, x2, y2, partials);
  else
    mmd_gemm<1><<<dim3(NBLK, 3), 256, 0, stream>>>(X, Y, x2, y2, partials);
  finalize_kernel<<<1, 256, 0, stream>>>(partials, (float*)d_out);
}

// Round 2
// 212.344 us; speedup vs baseline: 1.2306x; 1.2306x over previous
//
#include <hip/hip_runtime.h>
#include <stdint.h>
#include <stddef.h>

#define AS1 __attribute__((address_space(1)))
#define AS3 __attribute__((address_space(3)))

typedef short bf16x8 __attribute__((ext_vector_type(8)));
typedef float f32x4 __attribute__((ext_vector_type(4)));
typedef unsigned short u16x8 __attribute__((ext_vector_type(8)));

static constexpr int N = 4096;
static constexpr int K = 2048;
static constexpr int BM = 128;         // legacy fallback tile
static constexpr int TILES = N / BM;   // 32
static constexpr int NBLK = TILES * TILES;  // 1024 (fallback)

// round-to-nearest-even f32 -> bf16
__device__ __forceinline__ unsigned short f2bf(float f) {
  union { float f; uint32_t u; } v; v.f = f;
  return (unsigned short)((v.u + 0x7FFFu + ((v.u >> 16) & 1u)) >> 16);
}

__global__ __launch_bounds__(256) void prep_kernel(
    const float* __restrict__ X, const float* __restrict__ Y,
    float* __restrict__ x2, float* __restrict__ y2,
    unsigned short* __restrict__ Xb, unsigned short* __restrict__ Yb, int wb) {
  const int row = blockIdx.x;
  const float* src = blockIdx.y ? Y : X;
  float* nrm = blockIdx.y ? y2 : x2;
  unsigned short* dst = blockIdx.y ? Yb : Xb;
  const size_t base = (size_t)row * K + threadIdx.x * 8;
  const float4 a = *(const float4*)(src + base);
  const float4 b = *(const float4*)(src + base + 4);
  double s = (double)a.x * a.x + (double)a.y * a.y + (double)a.z * a.z +
             (double)a.w * a.w + (double)b.x * b.x + (double)b.y * b.y +
             (double)b.z * b.z + (double)b.w * b.w;
  if (wb) {
    u16x8 o;
    o[0] = f2bf(a.x); o[1] = f2bf(a.y); o[2] = f2bf(a.z); o[3] = f2bf(a.w);
    o[4] = f2bf(b.x); o[5] = f2bf(b.y); o[6] = f2bf(b.z); o[7] = f2bf(b.w);
    *(u16x8*)(dst + base) = o;
  }
#pragma unroll
  for (int off = 32; off; off >>= 1) s += __shfl_down(s, off);
  __shared__ double red[4];
  if ((threadIdx.x & 63) == 0) red[threadIdx.x >> 6] = s;
  __syncthreads();
  if (threadIdx.x == 0) nrm[row] = (float)(red[0] + red[1] + red[2] + red[3]);
}

// ---------------- 256^2 8-phase kernel (fast path) ----------------
// LDS per buffer: A[k0|k1] 2x8192 shorts, B[k0|k1] 2x8192 shorts = 32K shorts/buf.
// Storage: subtile (256 rows x 32 cols bf16), row stride 64B, 16B-chunk sc with
// logical chunk c stored at sc = (c + (r>>2)) & 3  (bank-conflict-free, 2-way max).

#define VM10 asm volatile("s_waitcnt vmcnt(10)" ::: "memory")
#define VM_NONE

#define STAGE(O, KS, TT, BB)                                                   \
  do {                                                                         \
    const unsigned short* _sp = (O) ? Bpan : Apan;                             \
    const unsigned int _kof = (unsigned)(TT) * 64u + (KS) * 32u;               \
    const unsigned int _lb = (BB) * 32768u + (O) * 16384u + (KS) * 8192u + wseg; \
    __builtin_amdgcn_global_load_lds(                                          \
        (const AS1 unsigned int*)(_sp + ((O) ? sB0 : sA0) + _kof),             \
        (AS3 unsigned int*)(lds + _lb), 16, 0, 0);                             \
    __builtin_amdgcn_global_load_lds(                                          \
        (const AS1 unsigned int*)(_sp + ((O) ? sB1 : sA1) + _kof),             \
        (AS3 unsigned int*)(lds + _lb + 512u), 16, 0, 0);                      \
  } while (0)

#define PHASE(KS, NH, BB, VMW, ...)                                            \
  do {                                                                         \
    if constexpr ((NH) == 0) {                                                 \
      _Pragma("unroll") for (int _mi = 0; _mi < 8; ++_mi)                      \
          af[_mi] = *(const bf16x8*)(lds + (BB) * 32768u + (KS) * 8192u +      \
                                     aoff[_mi]);                               \
    }                                                                          \
    bf16x8 _b0 = *(const bf16x8*)(lds + (BB) * 32768u + 16384u +               \
                                  (KS) * 8192u + boff[(NH) * 2]);              \
    bf16x8 _b1 = *(const bf16x8*)(lds + (BB) * 32768u + 16384u +               \
                                  (KS) * 8192u + boff[(NH) * 2 + 1]);          \
    __VA_ARGS__;                                                               \
    __builtin_amdgcn_s_barrier();                                              \
    __builtin_amdgcn_s_setprio(1);                                             \
    _Pragma("unroll") for (int _mi = 0; _mi < 8; ++_mi) {                      \
      acc[_mi][(NH) * 2] = __builtin_amdgcn_mfma_f32_16x16x32_bf16(            \
          af[_mi], _b0, acc[_mi][(NH) * 2], 0, 0, 0);                          \
      acc[_mi][(NH) * 2 + 1] = __builtin_amdgcn_mfma_f32_16x16x32_bf16(        \
          af[_mi], _b1, acc[_mi][(NH) * 2 + 1], 0, 0, 0);                      \
    }                                                                          \
    __builtin_amdgcn_s_setprio(0);                                             \
    VMW;                                                                       \
    __builtin_amdgcn_s_barrier();                                              \
  } while (0)

#define TILE(T, BB)                                                            \
  do {                                                                         \
    const int _t1 = ((T) + 1 < 32) ? (T) + 1 : 31;                             \
    const int _t2 = ((T) + 2 < 32) ? (T) + 2 : 31;                             \
    PHASE(0, 0, BB, VM_NONE, STAGE(1, 1, _t1, 1 - (BB)));                      \
    PHASE(0, 1, BB, VM10, STAGE(0, 0, _t2, BB));                               \
    PHASE(1, 0, BB, VM_NONE, STAGE(1, 0, _t2, BB));                            \
    PHASE(1, 1, BB, VM10, STAGE(0, 1, _t2, BB));                               \
  } while (0)

__global__ __launch_bounds__(512, 2) void mmd_gemm8(
    const unsigned short* __restrict__ Xb, const unsigned short* __restrict__ Yb,
    const float* __restrict__ x2, const float* __restrict__ y2,
    double* __restrict__ partials) {
  __shared__ __align__(16) unsigned short lds[65536];  // 128 KiB

  const int bid = blockIdx.x;
  const int logical = (bid & 7) * 96 + (bid >> 3);  // bijective XCD swizzle (768%8==0)
  const int p = logical >> 8;                        // 0:XX 1:YY 2:XY
  const int t = logical & 255;
  const int i0 = (t & 15) << 8;
  const int j0 = (t >> 4) << 8;

  const unsigned short* Apan = (p == 1) ? Yb : Xb;
  const unsigned short* Bpan = (p == 0) ? Xb : Yb;
  const float* rn = (p == 1) ? y2 : x2;
  const float* cn = (p == 0) ? x2 : y2;
  const double wgt = (p == 2) ? -2.0 : 1.0;

  const int tid = threadIdx.x;
  const int w = tid >> 6, l = tid & 63;
  const int wm = w >> 2, wn = w & 3;
  const int lr = l & 15, lq = l >> 4;

  // staging per-thread constants: chunkidx -> (row, stored-chunk) -> logical col
  const int ci0 = w * 128 + l;
  const int ci1 = ci0 + 64;
  const int r0 = ci0 >> 2, r1 = ci1 >> 2;
  const int c0 = ((ci0 & 3) - (r0 >> 2)) & 3;
  const int c1 = ((ci1 & 3) - (r1 >> 2)) & 3;
  const unsigned int sA0 = (unsigned)(i0 + r0) * (unsigned)K + (unsigned)(c0 * 8);
  const unsigned int sA1 = (unsigned)(i0 + r1) * (unsigned)K + (unsigned)(c1 * 8);
  const unsigned int sB0 = (unsigned)(j0 + r0) * (unsigned)K + (unsigned)(c0 * 8);
  const unsigned int sB1 = (unsigned)(j0 + r1) * (unsigned)K + (unsigned)(c1 * 8);
  const unsigned int wseg = (unsigned)w * 1024u;  // shorts: (w*2+u)*512

  // fragment read offsets (shorts, within a k-subtile)
  unsigned int aoff[8], boff[4];
#pragma unroll
  for (int mi = 0; mi < 8; ++mi) {
    const int r = wm * 128 + mi * 16 + lr;
    aoff[mi] = (unsigned)(r * 32 + (((lq + (r >> 2)) & 3) * 8));
  }
#pragma unroll
  for (int ni = 0; ni < 4; ++ni) {
    const int rb = wn * 64 + ni * 16 + lr;
    boff[ni] = (unsigned)(rb * 32 + (((lq + (rb >> 2)) & 3) * 8));
  }

  f32x4 acc[8][4] = {};
  bf16x8 af[8];

  // Prologue: tile0 (buf0) fully + tile1 (buf1) A_k0,B_k0,A_k1 = 14 loads/thread.
  STAGE(0, 0, 0, 0); STAGE(1, 0, 0, 0); STAGE(0, 1, 0, 0); STAGE(1, 1, 0, 0);
  STAGE(0, 0, 1, 1); STAGE(1, 0, 1, 1); STAGE(0, 1, 1, 1);
  VM10;  // retire A_k0(0), B_k0(0)
  __builtin_amdgcn_s_barrier();

#pragma unroll 1
  for (int tt = 0; tt < 32; tt += 2) {
    TILE(tt, 0);
    TILE(tt + 1, 1);
  }

  // Epilogue: expm1(-sqdist/D^2) Taylor; the "+1" cancels in 1/1/-2 weights.
  const float ce = -1.0f / (2048.0f * 2048.0f);
  double s = 0.0;
#pragma unroll
  for (int mi = 0; mi < 8; ++mi) {
#pragma unroll
    for (int r4 = 0; r4 < 4; ++r4) {
      const float rv = rn[i0 + wm * 128 + mi * 16 + lq * 4 + r4];
#pragma unroll
      for (int ni = 0; ni < 4; ++ni) {
        const float cv = cn[j0 + wn * 64 + ni * 16 + lr];
        const float tx = ce * (rv + cv - 2.0f * acc[mi][ni][r4]);
        const float v =
            tx * (1.0f + tx * (0.5f + tx * (0.16666667f + tx * 0.041666668f)));
        s += (double)v;
      }
    }
  }
#pragma unroll
  for (int off = 32; off; off >>= 1) s += __shfl_down(s, off);
  __shared__ double red[8];
  if (l == 0) red[w] = s;
  __syncthreads();
  if (tid == 0) {
    double tot = 0.0;
#pragma unroll
    for (int i = 0; i < 8; ++i) tot += red[i];
    partials[logical] = wgt * tot;
  }
}

// ---------------- legacy 128^2 kernel (ws-too-small fallback, f32 inputs) ----
__global__ __launch_bounds__(256) void mmd_gemm_f32(
    const float* __restrict__ Xp, const float* __restrict__ Yp,
    const float* __restrict__ x2, const float* __restrict__ y2,
    double* __restrict__ partials) {
  const int p = blockIdx.y;
  const float* Ap = (p == 1) ? Yp : Xp;
  const float* Bp = (p == 0) ? Xp : Yp;
  const float* rn = (p == 1) ? y2 : x2;
  const float* cn = (p == 0) ? x2 : y2;
  const double wgt = (p == 2) ? -2.0 : 1.0;

  const int bx = blockIdx.x;
  const int i0 = (bx & (TILES - 1)) * BM;
  const int j0 = (bx / TILES) * BM;

  __shared__ __align__(16) unsigned short As[BM * 64];
  __shared__ __align__(16) unsigned short Bs[BM * 64];

  const int tid = threadIdx.x;
  const int w = tid >> 6, l = tid & 63;
  const int m_base = (w >> 1) * 64, n_base = (w & 1) * 64;

  f32x4 acc[4][4] = {};

  for (int k0 = 0; k0 < K; k0 += 64) {
#pragma unroll
    for (int u = 0; u < 4; ++u) {
      const int f = u * 256 + tid;
      const int row = f >> 3;
      const int cir = f & 7;
      const int dstb = row * 128 + ((cir ^ (row & 7)) * 16);
      {
        const float* g = Ap + (size_t)(i0 + row) * K + k0 + cir * 8;
        const float4 v0 = *(const float4*)g;
        const float4 v1 = *(const float4*)(g + 4);
        u16x8 o;
        o[0] = f2bf(v0.x); o[1] = f2bf(v0.y); o[2] = f2bf(v0.z); o[3] = f2bf(v0.w);
        o[4] = f2bf(v1.x); o[5] = f2bf(v1.y); o[6] = f2bf(v1.z); o[7] = f2bf(v1.w);
        *(u16x8*)((char*)As + dstb) = o;
      }
      {
        const float* g = Bp + (size_t)(j0 + row) * K + k0 + cir * 8;
        const float4 v0 = *(const float4*)g;
        const float4 v1 = *(const float4*)(g + 4);
        u16x8 o;
        o[0] = f2bf(v0.x); o[1] = f2bf(v0.y); o[2] = f2bf(v0.z); o[3] = f2bf(v0.w);
        o[4] = f2bf(v1.x); o[5] = f2bf(v1.y); o[6] = f2bf(v1.z); o[7] = f2bf(v1.w);
        *(u16x8*)((char*)Bs + dstb) = o;
      }
    }
    __syncthreads();

#pragma unroll
    for (int kk = 0; kk < 64; kk += 32) {
      bf16x8 af2[4], bfr[4];
      const int lr = l & 15;
      const int ch = (kk >> 3) + (l >> 4);
#pragma unroll
      for (int mi = 0; mi < 4; ++mi) {
        const int r = m_base + mi * 16 + lr;
        af2[mi] = *(const bf16x8*)((const char*)As + r * 128 + ((ch ^ (r & 7)) * 16));
      }
#pragma unroll
      for (int ni = 0; ni < 4; ++ni) {
        const int r = n_base + ni * 16 + lr;
        bfr[ni] = *(const bf16x8*)((const char*)Bs + r * 128 + ((ch ^ (r & 7)) * 16));
      }
#pragma unroll
      for (int mi = 0; mi < 4; ++mi)
#pragma unroll
        for (int ni = 0; ni < 4; ++ni)
          acc[mi][ni] = __builtin_amdgcn_mfma_f32_16x16x32_bf16(
              af2[mi], bfr[ni], acc[mi][ni], 0, 0, 0);
    }
    __syncthreads();
  }

  const float ce = -1.0f / (2048.0f * 2048.0f);
  double s = 0.0;
  const int lr = l & 15, lq = l >> 4;
#pragma unroll
  for (int mi = 0; mi < 4; ++mi) {
#pragma unroll
    for (int r4 = 0; r4 < 4; ++r4) {
      const float rv = rn[i0 + m_base + mi * 16 + lq * 4 + r4];
#pragma unroll
      for (int ni = 0; ni < 4; ++ni) {
        const float cv = cn[j0 + n_base + ni * 16 + lr];
        const float tx = ce * (rv + cv - 2.0f * acc[mi][ni][r4]);
        const float v =
            tx * (1.0f + tx * (0.5f + tx * (0.16666667f + tx * 0.041666668f)));
        s += (double)v;
      }
    }
  }
#pragma unroll
  for (int off = 32; off; off >>= 1) s += __shfl_down(s, off);
  __shared__ double red[4];
  if (l == 0) red[w] = s;
  __syncthreads();
  if (tid == 0) partials[p * NBLK + bx] = wgt * (red[0] + red[1] + red[2] + red[3]);
}

__global__ __launch_bounds__(256) void finalize_kernel(
    const double* __restrict__ partials, float* __restrict__ out, int n) {
  double s = 0.0;
  for (int i = threadIdx.x; i < n; i += 256) s += partials[i];
#pragma unroll
  for (int off = 32; off; off >>= 1) s += __shfl_down(s, off);
  __shared__ double red[4];
  if ((threadIdx.x & 63) == 0) red[threadIdx.x >> 6] = s;
  __syncthreads();
  if (threadIdx.x == 0)
    out[0] = (float)((red[0] + red[1] + red[2] + red[3]) *
                     (1.0 / ((double)N * (double)N)));
}

extern "C" void kernel_launch(void* const* d_in, const int* in_sizes, int n_in,
                              void* d_out, int out_size, void* d_ws,
                              size_t ws_size, hipStream_t stream) {
  const float* X = (const float*)d_in[0];
  const float* Y = (const float*)d_in[1];
  char* ws = (char*)d_ws;

  double* partials = (double*)ws;                       // 3072 f64 max
  float* x2 = (float*)(ws + 24576);
  float* y2 = (float*)(ws + 24576 + 16384);
  unsigned short* Xb = (unsigned short*)(ws + 65536);
  unsigned short* Yb = Xb + (size_t)N * K;
  const size_t need_fast = (size_t)65536 + (size_t)2 * N * K * 2;
  const bool fast = ws_size >= need_fast;

  prep_kernel<<<dim3(N, 2), 256, 0, stream>>>(X, Y, x2, y2, Xb, Yb, fast ? 1 : 0);
  if (fast) {
    mmd_gemm8<<<dim3(768), dim3(512), 0, stream>>>(Xb, Yb, x2, y2, partials);
    finalize_kernel<<<1, 256, 0, stream>>>(partials, (float*)d_out, 768);
  } else {
    mmd_gemm_f32<<<dim3(NBLK, 3), 256, 0, stream>>>(X, Y, x2, y2, partials);
    finalize_kernel<<<1, 256, 0, stream>>>(partials, (float*)d_out, 3072);
  }
}